// Round 3
// baseline (204.862 us; speedup 1.0000x reference)
//
#include <hip/hip_runtime.h>
#include <math.h>

#define DIM   2048
#define NEXP  64
#define TPB   256
#define CH    32
#define XSTR  33    // LDS row stride (floats), odd => 2-way-max bank aliasing (free)

// ---------------- Kernel 1: partial logits, token-per-lane, W via SGPR ------
// grid = (n_tokens/TPB) * ks, block = 256. Each lane owns one token; its x
// chunk (32 floats) sits in VGPRs; W is wave-uniform => s_load into SGPRs and
// v_fma_f32 with SGPR operand. Inner loop has NO LDS and NO vector loads.
__global__ __launch_bounds__(256, 2)
void router_part(const float* __restrict__ x, const float* __restrict__ Wg,
                 float* __restrict__ part, int n_tokens, int KC) {
    __shared__ float xs[2][TPB][XSTR];   // 67.6 KB => 2 blocks/CU
    const int tid = threadIdx.x;
    const int tb  = blockIdx.x & 63;     // token block (n_tokens/TPB = 64)
    const int s   = blockIdx.x >> 6;     // K-split index
    const int t0  = tb * TPB;
    const int k0  = s * KC;

    float acc[NEXP];
#pragma unroll
    for (int e = 0; e < NEXP; ++e) acc[e] = 0.f;

    const float* xg = x + (size_t)t0 * DIM + k0;
    const int grow = tid >> 3;           // staging row base 0..31
    const int gcol = (tid & 7) * 4;      // float offset 0..28 (16B aligned)

    // stage chunk 0 (coalesced 128B per 8-lane group; scalar LDS writes, 2-way max)
#pragma unroll
    for (int p = 0; p < 8; ++p) {
        const int row = grow + p * 32;
        float4 v = *(const float4*)&xg[(size_t)row * DIM + gcol];
        xs[0][row][gcol + 0] = v.x;
        xs[0][row][gcol + 1] = v.y;
        xs[0][row][gcol + 2] = v.z;
        xs[0][row][gcol + 3] = v.w;
    }
    __syncthreads();

    const int nch = KC / CH;
    for (int c = 0; c < nch; ++c) {
        const int cur = c & 1;
        // prefetch next chunk into registers (HBM latency hides under FMAs)
        float4 pf[8];
        const bool nx = (c + 1 < nch);
        if (nx) {
#pragma unroll
            for (int p = 0; p < 8; ++p) {
                const int row = grow + p * 32;
                pf[p] = *(const float4*)&xg[(size_t)row * DIM + (c + 1) * CH + gcol];
            }
        }
        // own-token x chunk -> VGPRs (2-way bank aliasing = free)
        float xr[CH];
#pragma unroll
        for (int j = 0; j < CH; ++j) xr[j] = xs[cur][tid][j];

        // inner: 64 experts x 32 FMA; W address is uniform => s_load/SGPR
        const float* wb = Wg + k0 + c * CH;
        for (int e = 0; e < NEXP; ++e) {
#pragma unroll
            for (int j = 0; j < CH; ++j)
                acc[e] = fmaf(xr[j], wb[(size_t)e * DIM + j], acc[e]);
        }

        if (nx) {
            const int nxt = cur ^ 1;
#pragma unroll
            for (int p = 0; p < 8; ++p) {
                const int row = grow + p * 32;
                xs[nxt][row][gcol + 0] = pf[p].x;
                xs[nxt][row][gcol + 1] = pf[p].y;
                xs[nxt][row][gcol + 2] = pf[p].z;
                xs[nxt][row][gcol + 3] = pf[p].w;
            }
        }
        __syncthreads();
    }

    // write partials: part[s][token][expert], 16 aligned float4 stores
    float* pb = part + ((size_t)s * n_tokens + t0 + tid) * NEXP;
#pragma unroll
    for (int q = 0; q < NEXP / 4; ++q) {
        float4 v;
        v.x = acc[q * 4 + 0];
        v.y = acc[q * 4 + 1];
        v.z = acc[q * 4 + 2];
        v.w = acc[q * 4 + 3];
        *(float4*)&pb[q * 4] = v;
    }
}

// ---------------- Kernel 2: reduce partials + softmax + top-2 + aux ---------
#define FTPB 128
__global__ __launch_bounds__(FTPB)
void router_finish(const float* __restrict__ part, float* __restrict__ out,
                   float* __restrict__ gCnt, float* __restrict__ gPsum,
                   int n_tokens, int ks) {
    __shared__ float pl[FTPB][NEXP + 1];
    __shared__ float cnt[NEXP];
    const int tid = threadIdx.x;
    const int tok = blockIdx.x * FTPB + tid;
    if (tid < NEXP) cnt[tid] = 0.f;

    float lg[NEXP];
#pragma unroll
    for (int q = 0; q < NEXP / 4; ++q) {
        float4 a = *(const float4*)&part[(size_t)tok * NEXP + q * 4];
        lg[q * 4 + 0] = a.x; lg[q * 4 + 1] = a.y;
        lg[q * 4 + 2] = a.z; lg[q * 4 + 3] = a.w;
    }
    for (int s = 1; s < ks; ++s) {
#pragma unroll
        for (int q = 0; q < NEXP / 4; ++q) {
            float4 a = *(const float4*)&part[((size_t)s * n_tokens + tok) * NEXP + q * 4];
            lg[q * 4 + 0] += a.x; lg[q * 4 + 1] += a.y;
            lg[q * 4 + 2] += a.z; lg[q * 4 + 3] += a.w;
        }
    }

    // top-2 (strict > keeps lowest index on ties, matching lax.top_k)
    float m1 = -1e30f, m2 = -1e30f;
    int i1 = 0, i2 = 0;
#pragma unroll
    for (int e = 0; e < NEXP; ++e) {
        float l = lg[e];
        if (l > m1)      { m2 = m1; i2 = i1; m1 = l; i1 = e; }
        else if (l > m2) { m2 = l; i2 = e; }
    }

    float ssum = 0.f;
#pragma unroll
    for (int e = 0; e < NEXP; ++e) {
        float p = __expf(lg[e] - m1);
        lg[e] = p;
        ssum += p;
    }
    const float inv_s = 1.f / ssum;
#pragma unroll
    for (int e = 0; e < NEXP; ++e) pl[tid][e] = lg[e] * inv_s;

    const float p1 = inv_s;                      // exp(0)*inv_s
    const float p2 = __expf(m2 - m1) * inv_s;
    const float d  = p1 + p2 + 1e-8f;
    out[(size_t)tok * 2]     = (float)i1;
    out[(size_t)tok * 2 + 1] = (float)i2;
    out[(size_t)n_tokens * 2 + (size_t)tok * 2]     = p1 / d;
    out[(size_t)n_tokens * 2 + (size_t)tok * 2 + 1] = p2 / d;
    atomicAdd(&cnt[i1], 1.f);
    atomicAdd(&cnt[i2], 1.f);
    __syncthreads();

    if (tid < NEXP) {
        float cs = 0.f;
#pragma unroll 8
        for (int t = 0; t < FTPB; ++t) cs += pl[t][tid];
        atomicAdd(&gPsum[tid], cs);
        atomicAdd(&gCnt[tid], cnt[tid]);
    }
}

// ---------------- Kernel 3: final aux loss ----------------------------------
__global__ void router_aux(const float* __restrict__ gCnt,
                           const float* __restrict__ gPsum,
                           float* __restrict__ out, int n_tokens) {
    const int e = threadIdx.x;
    float f = gCnt[e] / (float)(n_tokens * 2);
    float P = gPsum[e] / (float)n_tokens;
    float v = f * P;
#pragma unroll
    for (int o = 32; o > 0; o >>= 1) v += __shfl_down(v, o);
    if (e == 0) out[(size_t)n_tokens * 4] = 64.f * v;
}

extern "C" void kernel_launch(void* const* d_in, const int* in_sizes, int n_in,
                              void* d_out, int out_size, void* d_ws, size_t ws_size,
                              hipStream_t stream) {
    const float* x  = (const float*)d_in[0];
    const float* Wg = (const float*)d_in[1];
    float* out = (float*)d_out;
    const int n_tokens = in_sizes[0] / DIM;   // 16384

    // pick largest K-split whose partial buffer fits the workspace
    int ks = 8;
    while (ks > 1 &&
           (2 * NEXP + (size_t)ks * n_tokens * NEXP) * sizeof(float) > ws_size)
        ks >>= 1;
    const int KC = DIM / ks;

    float* gCnt  = (float*)d_ws;
    float* gPsum = gCnt + NEXP;
    float* partb = gPsum + NEXP;

    hipMemsetAsync(d_ws, 0, 2 * NEXP * sizeof(float), stream);
    hipLaunchKernelGGL(router_part, dim3((n_tokens / TPB) * ks), dim3(TPB), 0, stream,
                       x, Wg, partb, n_tokens, KC);
    hipLaunchKernelGGL(router_finish, dim3(n_tokens / FTPB), dim3(FTPB), 0, stream,
                       partb, out, gCnt, gPsum, n_tokens, ks);
    hipLaunchKernelGGL(router_aux, dim3(1), dim3(NEXP), 0, stream,
                       gCnt, gPsum, out, n_tokens);
}